// Round 4
// baseline (294.364 us; speedup 1.0000x reference)
//
#include <hip/hip_runtime.h>
#include <hip/hip_bf16.h>
#include <stdint.h>

#define TOKENS 8192
#define IN_F   4096
#define OUT_F  4096

typedef __attribute__((ext_vector_type(4))) float  f32x4;
typedef __attribute__((ext_vector_type(8))) __bf16 bf16x8;

__device__ __forceinline__ unsigned short f2bf(float f) {
    union { float f; uint32_t u; } c; c.f = f;
    uint32_t u = c.u;
    u += 0x7fffu + ((u >> 16) & 1);   // round-to-nearest-even
    return (unsigned short)(u >> 16);
}

__device__ __forceinline__ void load_lds_16(const void* gptr, void* lptr) {
    __builtin_amdgcn_global_load_lds(
        (const __attribute__((address_space(1))) unsigned int*)gptr,
        (__attribute__((address_space(3))) unsigned int*)lptr, 16, 0, 0);
}

// m201 phase shape: reads issued BEFORE the barrier, lgkmcnt(0) after it,
// then a pure-MFMA cluster. Rule #18: sched_barrier(0) right after the
// inline-asm lgkmcnt so MFMAs can't hoist above the wait.
__device__ __forceinline__ void open_bar() {
    asm volatile("s_barrier\ns_waitcnt lgkmcnt(0)" ::: "memory");
    __builtin_amdgcn_sched_barrier(0);
}
__device__ __forceinline__ void cbar() { asm volatile("s_barrier" ::: "memory"); }
template<int W> __device__ __forceinline__ void cbar_w() {
    if constexpr (W == 8)      asm volatile("s_waitcnt vmcnt(8)\ns_barrier" ::: "memory");
    else if constexpr (W == 4) asm volatile("s_waitcnt vmcnt(4)\ns_barrier" ::: "memory");
    else                       asm volatile("s_waitcnt vmcnt(0)\ns_barrier" ::: "memory");
}

// ---------------- prep: x fp32 -> bf16 ----------------
__global__ __launch_bounds__(256) void cvt_x_kernel(const float* __restrict__ x,
                                                    unsigned short* __restrict__ xb, int n4) {
    int i = blockIdx.x * blockDim.x + threadIdx.x;
    int stride = gridDim.x * blockDim.x;
    for (; i < n4; i += stride) {
        float4 v = ((const float4*)x)[i];
        ushort4 o;
        o.x = f2bf(v.x); o.y = f2bf(v.y); o.z = f2bf(v.z); o.w = f2bf(v.w);
        ((ushort4*)xb)[i] = o;
    }
}

// ---------------- prep: W_eff = W*(1+mask) fp32 -> bf16 ----------------
__global__ __launch_bounds__(256) void cvt_w_kernel(const float* __restrict__ w,
                                                    const int* __restrict__ mask,
                                                    unsigned short* __restrict__ wb) {
    const int n4 = OUT_F * IN_F / 4;
    int i = blockIdx.x * blockDim.x + threadIdx.x;
    int stride = gridDim.x * blockDim.x;
    for (; i < n4; i += stride) {
        int elem = i * 4;
        int o = elem >> 12;
        int k = elem & (IN_F - 1);
        int mb = mask[(o >> 4) * (IN_F / 16) + (k >> 4)];
        float s = mb ? 2.0f : 1.0f;
        float4 v = ((const float4*)w)[i];
        ushort4 ov;
        ov.x = f2bf(v.x * s); ov.y = f2bf(v.y * s);
        ov.z = f2bf(v.z * s); ov.w = f2bf(v.w * s);
        ((ushort4*)wb)[i] = ov;
    }
}

// ------- 256x256 8-wave, ks-half 4-phase, 1.5-tile-deep pipeline -------
// LDS layout (shorts): A[buf][ksh] at buf*16384 + ksh*8192  (rows x 32)
//                      B[buf][ksh] at 32768 + buf*16384 + ksh*8192
// Swizzle: chunk c (0..3, 8-short units) XOR (row>>1)&3 -> 2-way banks (free).
#define BM 256
#define BN 256
#define BK 64
#define NT (IN_F / BK)   // 64

#define RD_B(KS) {                                                             \
    const unsigned short* pB_ = sm + 32768 + bcur * 16384 + (KS) * 8192 + b_base; \
    bb0 = *(const bf16x8*)(pB_);        bb1 = *(const bf16x8*)(pB_ + 512);     \
    bb2 = *(const bf16x8*)(pB_ + 1024); bb3 = *(const bf16x8*)(pB_ + 1536); }

#define RD_A(KS, MH) {                                                         \
    const unsigned short* pA_ = sm + bcur * 16384 + (KS) * 8192 + a_base + (MH) * 2048; \
    aa0 = *(const bf16x8*)(pA_);        aa1 = *(const bf16x8*)(pA_ + 512);     \
    aa2 = *(const bf16x8*)(pA_ + 1024); aa3 = *(const bf16x8*)(pA_ + 1536); }

#define MM16(MH) {                                                             \
    __builtin_amdgcn_s_setprio(1);                                             \
    acc[(MH)*4+0][0] = __builtin_amdgcn_mfma_f32_16x16x32_bf16(aa0, bb0, acc[(MH)*4+0][0], 0, 0, 0); \
    acc[(MH)*4+0][1] = __builtin_amdgcn_mfma_f32_16x16x32_bf16(aa0, bb1, acc[(MH)*4+0][1], 0, 0, 0); \
    acc[(MH)*4+0][2] = __builtin_amdgcn_mfma_f32_16x16x32_bf16(aa0, bb2, acc[(MH)*4+0][2], 0, 0, 0); \
    acc[(MH)*4+0][3] = __builtin_amdgcn_mfma_f32_16x16x32_bf16(aa0, bb3, acc[(MH)*4+0][3], 0, 0, 0); \
    acc[(MH)*4+1][0] = __builtin_amdgcn_mfma_f32_16x16x32_bf16(aa1, bb0, acc[(MH)*4+1][0], 0, 0, 0); \
    acc[(MH)*4+1][1] = __builtin_amdgcn_mfma_f32_16x16x32_bf16(aa1, bb1, acc[(MH)*4+1][1], 0, 0, 0); \
    acc[(MH)*4+1][2] = __builtin_amdgcn_mfma_f32_16x16x32_bf16(aa1, bb2, acc[(MH)*4+1][2], 0, 0, 0); \
    acc[(MH)*4+1][3] = __builtin_amdgcn_mfma_f32_16x16x32_bf16(aa1, bb3, acc[(MH)*4+1][3], 0, 0, 0); \
    acc[(MH)*4+2][0] = __builtin_amdgcn_mfma_f32_16x16x32_bf16(aa2, bb0, acc[(MH)*4+2][0], 0, 0, 0); \
    acc[(MH)*4+2][1] = __builtin_amdgcn_mfma_f32_16x16x32_bf16(aa2, bb1, acc[(MH)*4+2][1], 0, 0, 0); \
    acc[(MH)*4+2][2] = __builtin_amdgcn_mfma_f32_16x16x32_bf16(aa2, bb2, acc[(MH)*4+2][2], 0, 0, 0); \
    acc[(MH)*4+2][3] = __builtin_amdgcn_mfma_f32_16x16x32_bf16(aa2, bb3, acc[(MH)*4+2][3], 0, 0, 0); \
    acc[(MH)*4+3][0] = __builtin_amdgcn_mfma_f32_16x16x32_bf16(aa3, bb0, acc[(MH)*4+3][0], 0, 0, 0); \
    acc[(MH)*4+3][1] = __builtin_amdgcn_mfma_f32_16x16x32_bf16(aa3, bb1, acc[(MH)*4+3][1], 0, 0, 0); \
    acc[(MH)*4+3][2] = __builtin_amdgcn_mfma_f32_16x16x32_bf16(aa3, bb2, acc[(MH)*4+3][2], 0, 0, 0); \
    acc[(MH)*4+3][3] = __builtin_amdgcn_mfma_f32_16x16x32_bf16(aa3, bb3, acc[(MH)*4+3][3], 0, 0, 0); \
    __builtin_amdgcn_s_setprio(0); }

// stage one (tile T, ks-half H) operand pair: 2 x global_load_lds (rows r*128..)
#define ST_A(T, H) {                                                           \
    const unsigned short* s_ = srcA + (size_t)(T) * 64 + (H) * 32;             \
    unsigned short* d_ = sm + (((T) & 1) * 16384 + (H) * 8192) + dstA;         \
    load_lds_16(s_, d_);                                                       \
    load_lds_16(s_ + (size_t)128 * IN_F, d_ + 4096); }
#define ST_B(T, H) {                                                           \
    const unsigned short* s_ = srcB + (size_t)(T) * 64 + (H) * 32;             \
    unsigned short* d_ = sm + (32768 + ((T) & 1) * 16384 + (H) * 8192) + dstB; \
    load_lds_16(s_, d_);                                                       \
    load_lds_16(s_ + (size_t)128 * IN_F, d_ + 4096); }

// One K-tile = 4 phases. Closing waits: vmcnt only at p1/p3 (data guards);
// plain barriers at p0/p2. Steady state W1=W3=8 (loads span ~6 phases).
#define KTILE(S1, S2, W1, W3, TN)                                              \
  {                                                                            \
    RD_B(0) RD_A(0, 0)                                                         \
    if (S1) ST_A(TN, 1)                                                        \
    open_bar(); MM16(0) cbar();                                                \
    RD_A(0, 1)                                                                 \
    if (S1) ST_B(TN, 1)                                                        \
    open_bar(); MM16(1) cbar_w<W1>();                                          \
    RD_B(1) RD_A(1, 0)                                                         \
    if (S2) ST_A((TN) + 1, 0)                                                  \
    open_bar(); MM16(0) cbar();                                                \
    RD_A(1, 1)                                                                 \
    if (S2) ST_B((TN) + 1, 0)                                                  \
    open_bar(); MM16(1) cbar_w<W3>();                                          \
  }

__global__ __launch_bounds__(512, 2) void gemm8_kernel(const unsigned short* __restrict__ A,
                                                       const unsigned short* __restrict__ B,
                                                       const float* __restrict__ bias,
                                                       float* __restrict__ C) {
    extern __shared__ __align__(16) unsigned short sm[];   // 128KB dynamic

    const int tid  = threadIdx.x;
    const int lane = tid & 63;
    const int wid  = tid >> 6;
    const int wr   = wid >> 2;       // 0..1 -> 128-row span
    const int wc   = wid & 3;        // 0..3 -> 64-col span

    const int nwg = (TOKENS / BM) * (OUT_F / BN);   // 512, %8==0
    int bid = blockIdx.x;
    int swz = (bid & 7) * (nwg >> 3) + (bid >> 3);  // XCD-aware swizzle
    const int tiles_n = OUT_F / BN;                 // 16
    const int t0 = (swz / tiles_n) * BM;
    const int o0 = (swz % tiles_n) * BN;

    // ---- staging constants (pre-swizzled global source, wave-linear dest) ----
    const int srow = tid >> 2;                      // 0..127
    const int sc   = tid & 3;                       // chunk 0..3 (8 shorts)
    const int scs  = sc ^ ((srow >> 1) & 3);        // swizzled source chunk
    const unsigned short* srcA = A + (size_t)(t0 + srow) * IN_F + scs * 8;
    const unsigned short* srcB = B + (size_t)(o0 + srow) * IN_F + scs * 8;
    const int dstA = srow * 32 + sc * 8;            // shorts; +4096 for r=1
    const int dstB = dstA;

    // ---- fragment-read bases (shorts), same swizzle ----
    const int l15 = lane & 15, q = lane >> 4;
    const int qe = q ^ ((l15 >> 1) & 3);
    const int a_base = (wr * 128 + l15) * 32 + qe * 8;   // + mf*512
    const int b_base = (wc * 64 + l15) * 32 + qe * 8;    // + nf*512

    f32x4 acc[8][4];
#pragma unroll
    for (int i = 0; i < 8; ++i)
#pragma unroll
        for (int j = 0; j < 4; ++j) acc[i][j] = (f32x4)0.0f;

    bf16x8 aa0, aa1, aa2, aa3, bb0, bb1, bb2, bb3;

    // ---- prologue: 3 half-tiles in flight (H0, H1, H2 = 12 loads) ----
    ST_A(0, 0) ST_B(0, 0)       // H0
    ST_A(0, 1) ST_B(0, 1)       // H1
    ST_A(1, 0) ST_B(1, 0)       // H2
    cbar_w<8>();                // H0 landed; 8 outstanding

    for (int kt = 0; kt < NT - 2; ++kt) {
        const int bcur = kt & 1;
        KTILE(true, true, 8, 8, kt + 1)
    }
    {   const int bcur = (NT - 2) & 1;
        KTILE(true, false, 8, 4, NT - 1)
    }
    {   const int bcur = (NT - 1) & 1;
        KTILE(false, false, 0, 0, NT)
    }

    // ---- epilogue: C/D layout col = lane&15, row = (lane>>4)*4 + reg ----
    float bv[4];
#pragma unroll
    for (int nf = 0; nf < 4; ++nf) bv[nf] = bias[o0 + wc * 64 + nf * 16 + l15];
#pragma unroll
    for (int mf = 0; mf < 8; ++mf) {
        const int t = t0 + wr * 128 + mf * 16 + q * 4;
#pragma unroll
        for (int nf = 0; nf < 4; ++nf) {
            const int o = o0 + wc * 64 + nf * 16 + l15;
#pragma unroll
            for (int r = 0; r < 4; ++r)
                C[(size_t)(t + r) * OUT_F + o] = acc[mf][nf][r] + bv[nf];
        }
    }
}

// ---------------- fp32 fallback (only if ws too small) ----------------
__global__ __launch_bounds__(256) void gemm_f32_fallback(const float* __restrict__ x,
                                                         const float* __restrict__ w,
                                                         const float* __restrict__ bias,
                                                         const int* __restrict__ mask,
                                                         float* __restrict__ out) {
    __shared__ float As[64][17];
    __shared__ float Bs[64][17];
    int bid = blockIdx.x;
    const int tiles_n = OUT_F / 64;
    int tm = bid / tiles_n, tn = bid % tiles_n;
    int t0 = tm * 64, o0 = tn * 64;
    int tid = threadIdx.x;
    int tx = tid & 15, ty = tid >> 4;
    int lrow = tid >> 2, lc4 = (tid & 3) * 4;
    float acc[4][4] = {};
    for (int k0 = 0; k0 < IN_F; k0 += 16) {
        float4 av = *(const float4*)&x[(size_t)(t0 + lrow) * IN_F + k0 + lc4];
        float4 bv = *(const float4*)&w[(size_t)(o0 + lrow) * IN_F + k0 + lc4];
        int mb = mask[((o0 + lrow) >> 4) * (IN_F / 16) + ((k0 + lc4) >> 4)];
        float s = mb ? 2.0f : 1.0f;
        As[lrow][lc4 + 0] = av.x; As[lrow][lc4 + 1] = av.y;
        As[lrow][lc4 + 2] = av.z; As[lrow][lc4 + 3] = av.w;
        Bs[lrow][lc4 + 0] = bv.x * s; Bs[lrow][lc4 + 1] = bv.y * s;
        Bs[lrow][lc4 + 2] = bv.z * s; Bs[lrow][lc4 + 3] = bv.w * s;
        __syncthreads();
#pragma unroll
        for (int kk = 0; kk < 16; ++kk) {
            float av2[4], bv2[4];
#pragma unroll
            for (int i = 0; i < 4; ++i) av2[i] = As[ty * 4 + i][kk];
#pragma unroll
            for (int j = 0; j < 4; ++j) bv2[j] = Bs[tx * 4 + j][kk];
#pragma unroll
            for (int i = 0; i < 4; ++i)
#pragma unroll
                for (int j = 0; j < 4; ++j) acc[i][j] += av2[i] * bv2[j];
        }
        __syncthreads();
    }
#pragma unroll
    for (int j = 0; j < 4; ++j) {
        int o = o0 + tx * 4 + j;
        float bv = bias[o];
#pragma unroll
        for (int i = 0; i < 4; ++i)
            out[(size_t)(t0 + ty * 4 + i) * OUT_F + o] = acc[i][j] + bv;
    }
}

extern "C" void kernel_launch(void* const* d_in, const int* in_sizes, int n_in,
                              void* d_out, int out_size, void* d_ws, size_t ws_size,
                              hipStream_t stream) {
    const float* x    = (const float*)d_in[0];
    const float* wgt  = (const float*)d_in[1];
    const float* bias = (const float*)d_in[2];
    const int*   mask = (const int*)d_in[3];
    float* out = (float*)d_out;

    size_t xb_bytes = (size_t)TOKENS * IN_F * 2;
    size_t wb_bytes = (size_t)OUT_F * IN_F * 2;

    if (ws_size >= xb_bytes + wb_bytes) {
        unsigned short* xb = (unsigned short*)d_ws;
        unsigned short* wb = (unsigned short*)((char*)d_ws + xb_bytes);
        hipLaunchKernelGGL(cvt_x_kernel, dim3(2048), dim3(256), 0, stream, x, xb, TOKENS * IN_F / 4);
        hipLaunchKernelGGL(cvt_w_kernel, dim3(1024), dim3(256), 0, stream, wgt, mask, wb);
        (void)hipFuncSetAttribute((const void*)gemm8_kernel,
                                  hipFuncAttributeMaxDynamicSharedMemorySize, 131072);
        hipLaunchKernelGGL(gemm8_kernel, dim3((TOKENS / BM) * (OUT_F / BN)), dim3(512),
                           131072, stream, xb, wb, bias, out);
    } else {
        hipLaunchKernelGGL(gemm_f32_fallback, dim3((TOKENS / 64) * (OUT_F / 64)), dim3(256), 0, stream,
                           x, wgt, bias, mask, out);
    }
}